// Round 1
// baseline (650.204 us; speedup 1.0000x reference)
//
#include <hip/hip_runtime.h>
#include <hip/hip_bf16.h>

#define BATCH 32
#define SEQ   2048
#define HID   1024
#define M     (BATCH*SEQ)

#define BM 128
#define BN 256
#define BK 32
#define PK 40   // padded LDS K-stride (bf16 elems): 80B rows -> only 2-way bank aliasing

typedef __attribute__((ext_vector_type(8))) short          bf16x8;
typedef __attribute__((ext_vector_type(8))) unsigned short us8;
typedef __attribute__((ext_vector_type(4))) float          f32x4;

__device__ __forceinline__ unsigned short f2bf_rn(float x) {
    unsigned u = __float_as_uint(x);
    unsigned r = (u + 0x7fffu + ((u >> 16) & 1u)) >> 16;
    return (unsigned short)r;
}
__device__ __forceinline__ float bf2f(unsigned short h) {
    return __uint_as_float(((unsigned)h) << 16);
}
__device__ __forceinline__ void split2(float x, unsigned short& h, unsigned short& l) {
    h = f2bf_rn(x);
    l = f2bf_rn(x - bf2f(h));
}

// ---------------- kernel 0: W f32 -> bf16 hi/lo (row-major [o][h]) ----------
__global__ __launch_bounds__(256) void k_convW(const float* __restrict__ W,
                                               unsigned short* __restrict__ w_hi,
                                               unsigned short* __restrict__ w_lo) {
    int i = (blockIdx.x * 256 + threadIdx.x) * 4;
    float4 w = *(const float4*)(W + i);
    float wv[4] = {w.x, w.y, w.z, w.w};
    unsigned short h[4], l[4];
#pragma unroll
    for (int j = 0; j < 4; j++) split2(wv[j], h[j], l[j]);
    *(ushort4*)(w_hi + i) = make_ushort4(h[0], h[1], h[2], h[3]);
    *(ushort4*)(w_lo + i) = make_ushort4(l[0], l[1], l[2], l[3]);
}

// ------ kernel 1: fused (enc+hidden) @ W^T -> tanh -> dot(v) -> pscore ------
__global__ __launch_bounds__(512) void k_gemm_scores(
    const float* __restrict__ enc,      // [M, HID]
    const float* __restrict__ hidden,   // [BATCH, HID]
    const unsigned short* __restrict__ w_hi,  // [HID,HID] row-major (o major)
    const unsigned short* __restrict__ w_lo,
    const float* __restrict__ b_attn,   // [HID]
    const float* __restrict__ v,        // [HID]
    float* __restrict__ pscore)         // [4][M]
{
    __shared__ unsigned short aH[BM][PK], aL[BM][PK];
    __shared__ unsigned short bH[BN][PK], bL[BN][PK];
    __shared__ float sc[BM];

    const int tid   = threadIdx.x;
    const int mblk  = blockIdx.x;          // 0..511
    const int nblk  = blockIdx.y;          // 0..3
    const int mbase = mblk * BM;
    const int nbase = nblk * BN;
    const int bidx  = mbase / SEQ;         // batch index (BM divides SEQ)

    const int lane = tid & 63;
    const int wid  = tid >> 6;             // 0..7
    const int wm   = wid >> 2;             // 0..1  (64-row block)
    const int wn   = wid & 3;              // 0..3  (64-col block)

    // staging coords
    const int arow = tid >> 2;             // 0..127
    const int acol = (tid & 3) * 8;        // 0,8,16,24
    const int brow = tid >> 1;             // 0..255
    const int bcol = (tid & 1) * 16;       // 0,16

    f32x4 acc[4][4];
#pragma unroll
    for (int i = 0; i < 4; i++)
#pragma unroll
        for (int j = 0; j < 4; j++) acc[i][j] = (f32x4)0.f;

    const int fr = lane & 15;
    const int fk = (lane >> 4) * 8;

    for (int kt = 0; kt < HID; kt += BK) {
        __syncthreads();
        // ---- stage A: x = enc + hidden, split to bf16 hi/lo ----
        {
            const float* ep = enc + (size_t)(mbase + arow) * HID + kt + acol;
            const float* hp = hidden + (size_t)bidx * HID + kt + acol;
            float4 e0 = *(const float4*)ep;
            float4 e1 = *(const float4*)(ep + 4);
            float4 h0 = *(const float4*)hp;
            float4 h1 = *(const float4*)(hp + 4);
            float xs[8] = {e0.x + h0.x, e0.y + h0.y, e0.z + h0.z, e0.w + h0.w,
                           e1.x + h1.x, e1.y + h1.y, e1.z + h1.z, e1.w + h1.w};
            us8 hv, lv;
#pragma unroll
            for (int j = 0; j < 8; j++) {
                unsigned short h, l;
                split2(xs[j], h, l);
                hv[j] = h; lv[j] = l;
            }
            *(us8*)&aH[arow][acol] = hv;
            *(us8*)&aL[arow][acol] = lv;
        }
        // ---- stage B: copy w_hi/w_lo tiles [BN][BK] ----
        {
            const unsigned short* whp = w_hi + (size_t)(nbase + brow) * HID + kt + bcol;
            const unsigned short* wlp = w_lo + (size_t)(nbase + brow) * HID + kt + bcol;
            us8 h0 = *(const us8*)whp;
            us8 h1 = *(const us8*)(whp + 8);
            us8 l0 = *(const us8*)wlp;
            us8 l1 = *(const us8*)(wlp + 8);
            *(us8*)&bH[brow][bcol]     = h0;
            *(us8*)&bH[brow][bcol + 8] = h1;
            *(us8*)&bL[brow][bcol]     = l0;
            *(us8*)&bL[brow][bcol + 8] = l1;
        }
        __syncthreads();

        // ---- fragments + MFMA (3-pass hi/lo) ----
        bf16x8 ah[4], al[4];
#pragma unroll
        for (int i = 0; i < 4; i++) {
            int mr = wm * 64 + i * 16 + fr;
            ah[i] = *(const bf16x8*)&aH[mr][fk];
            al[i] = *(const bf16x8*)&aL[mr][fk];
        }
#pragma unroll
        for (int j = 0; j < 4; j++) {
            int nr = wn * 64 + j * 16 + fr;
            bf16x8 bh = *(const bf16x8*)&bH[nr][fk];
            bf16x8 bl = *(const bf16x8*)&bL[nr][fk];
#pragma unroll
            for (int i = 0; i < 4; i++) {
                acc[i][j] = __builtin_amdgcn_mfma_f32_16x16x32_bf16(ah[i], bh, acc[i][j], 0, 0, 0);
                acc[i][j] = __builtin_amdgcn_mfma_f32_16x16x32_bf16(al[i], bh, acc[i][j], 0, 0, 0);
                acc[i][j] = __builtin_amdgcn_mfma_f32_16x16x32_bf16(ah[i], bl, acc[i][j], 0, 0, 0);
            }
        }
    }

    // ---- epilogue: tanh(e+b)*v, reduce over n, accumulate per-row ----
    __syncthreads();
    if (tid < BM) sc[tid] = 0.f;
    __syncthreads();

    const int g = lane >> 4;
    float rowsum[16];
#pragma unroll
    for (int t = 0; t < 16; t++) rowsum[t] = 0.f;

#pragma unroll
    for (int j = 0; j < 4; j++) {
        int n = nbase + wn * 64 + j * 16 + fr;
        float ba = b_attn[n];
        float vv = v[n];
#pragma unroll
        for (int i = 0; i < 4; i++) {
#pragma unroll
            for (int r = 0; r < 4; r++) {
                float e = tanhf(acc[i][j][r] + ba);
                rowsum[i * 4 + r] += e * vv;
            }
        }
    }
    // butterfly reduce across the 16 lanes of each group (cols)
#pragma unroll
    for (int off = 1; off < 16; off <<= 1) {
#pragma unroll
        for (int t = 0; t < 16; t++) rowsum[t] += __shfl_xor(rowsum[t], off, 64);
    }
    // lane (l&15)==j holds full sum; lane j writes row (j>>2)*16 + g*4 + (j&3)
    {
        int rloc = wm * 64 + (fr >> 2) * 16 + g * 4 + (fr & 3);
        atomicAdd(&sc[rloc], rowsum[fr]);
    }
    __syncthreads();
    if (tid < BM) pscore[(size_t)nblk * M + mbase + tid] = sc[tid];
}

// ---------------- kernel 2: sum partials + softmax over S -------------------
__global__ __launch_bounds__(256) void k_softmax(const float* __restrict__ pscore,
                                                 float* __restrict__ out) {
    const int b = blockIdx.x, t = threadIdx.x;
    __shared__ float red[8];
    float loc[8];
    float lmax = -1e30f;
#pragma unroll
    for (int i = 0; i < 8; i++) {
        int s = t + i * 256;
        float scv = 0.f;
#pragma unroll
        for (int p = 0; p < 4; p++) scv += pscore[(size_t)p * M + b * SEQ + s];
        loc[i] = scv;
        lmax = fmaxf(lmax, scv);
    }
    for (int o = 32; o; o >>= 1) lmax = fmaxf(lmax, __shfl_xor(lmax, o, 64));
    if ((t & 63) == 0) red[t >> 6] = lmax;
    __syncthreads();
    float bmax = fmaxf(fmaxf(red[0], red[1]), fmaxf(red[2], red[3]));
    float ev[8];
    float lsum = 0.f;
#pragma unroll
    for (int i = 0; i < 8; i++) {
        ev[i] = expf(loc[i] - bmax);
        lsum += ev[i];
    }
    for (int o = 32; o; o >>= 1) lsum += __shfl_xor(lsum, o, 64);
    __syncthreads();
    if ((t & 63) == 0) red[4 + (t >> 6)] = lsum;
    __syncthreads();
    float inv = 1.f / (red[4] + red[5] + red[6] + red[7]);
#pragma unroll
    for (int i = 0; i < 8; i++)
        out[(size_t)BATCH * HID + (size_t)b * SEQ + t + i * 256] = ev[i] * inv;
}

// ---------------- kernel 3: partial context over S-chunks -------------------
__global__ __launch_bounds__(256) void k_pctx(const float* __restrict__ enc,
                                              const float* __restrict__ attn,
                                              float* __restrict__ pctx) {
    const int hc = blockIdx.x;   // 0..3
    const int scb = blockIdx.y;  // 0..7
    const int b = blockIdx.z;    // 0..31
    const int h = hc * 256 + threadIdx.x;
    const float* ap = attn + (size_t)b * SEQ + scb * 256;
    const float* ep = enc + ((size_t)b * SEQ + scb * 256) * HID + h;
    float acc = 0.f;
#pragma unroll 4
    for (int s = 0; s < 256; s++) acc += ap[s] * ep[(size_t)s * HID];
    pctx[((size_t)scb * BATCH + b) * HID + h] = acc;
}

// ---------------- kernel 4: reduce partial contexts -------------------------
__global__ __launch_bounds__(256) void k_ctx(const float* __restrict__ pctx,
                                             float* __restrict__ out) {
    int i = blockIdx.x * 256 + threadIdx.x;  // 0..32767
    float a = 0.f;
#pragma unroll
    for (int p = 0; p < 8; p++) a += pctx[(size_t)p * BATCH * HID + i];
    out[i] = a;
}

extern "C" void kernel_launch(void* const* d_in, const int* in_sizes, int n_in,
                              void* d_out, int out_size, void* d_ws, size_t ws_size,
                              hipStream_t stream) {
    const float* hidden = (const float*)d_in[0];
    const float* enc    = (const float*)d_in[1];
    const float* W      = (const float*)d_in[2];
    const float* b_attn = (const float*)d_in[3];
    const float* v      = (const float*)d_in[4];
    float* out = (float*)d_out;

    char* ws = (char*)d_ws;
    unsigned short* w_hi = (unsigned short*)ws;                          // 2 MB
    unsigned short* w_lo = (unsigned short*)(ws + ((size_t)2 << 20));    // 2 MB
    float* pscore        = (float*)(ws + ((size_t)4 << 20));             // 1 MB
    float* pctx          = (float*)(ws + ((size_t)5 << 20));             // 1 MB

    k_convW<<<dim3(1024), dim3(256), 0, stream>>>(W, w_hi, w_lo);
    k_gemm_scores<<<dim3(M / BM, HID / BN), dim3(512), 0, stream>>>(
        enc, hidden, w_hi, w_lo, b_attn, v, pscore);
    k_softmax<<<dim3(BATCH), dim3(256), 0, stream>>>(pscore, out);
    k_pctx<<<dim3(4, 8, BATCH), dim3(256), 0, stream>>>(enc, out + BATCH * HID, pctx);
    k_ctx<<<dim3(128), dim3(256), 0, stream>>>(pctx, out);
}

// Round 2
// 433.643 us; speedup vs baseline: 1.4994x; 1.4994x over previous
//
#include <hip/hip_runtime.h>
#include <hip/hip_bf16.h>

#define BATCH 32
#define SEQ   2048
#define HID   1024
#define M_TOT (BATCH*SEQ)
#define NG    32          // K groups of 32 (each does xh*wh, xh*wl, xl*wh)

typedef __attribute__((ext_vector_type(8))) short          bf16x8;
typedef __attribute__((ext_vector_type(8))) unsigned short us8;
typedef __attribute__((ext_vector_type(4))) float          f32x4;

__device__ __forceinline__ unsigned short f2bf_rn(float x) {
    unsigned u = __float_as_uint(x);
    return (unsigned short)((u + 0x7fffu + ((u >> 16) & 1u)) >> 16);
}
__device__ __forceinline__ float bf2f(unsigned short h) {
    return __uint_as_float(((unsigned)h) << 16);
}

using as1_cv = const __attribute__((address_space(1))) void;
using as3_v  = __attribute__((address_space(3))) void;
__device__ __forceinline__ void gload16(const void* g, char* s) {
    __builtin_amdgcn_global_load_lds((as1_cv*)g, (as3_v*)s, 16, 0, 0);
}

#define FENCE() asm volatile("" ::: "memory")
#define BAR_LG() do { asm volatile("s_waitcnt lgkmcnt(0)" ::: "memory"); \
                      __builtin_amdgcn_s_barrier(); FENCE(); } while (0)
#define BAR_VM4() do { asm volatile("s_waitcnt vmcnt(4) lgkmcnt(0)" ::: "memory"); \
                       __builtin_amdgcn_s_barrier(); FENCE(); } while (0)

#define MFMA_BLK(A4, B4, IB) do { \
  _Pragma("unroll") for (int i_ = 0; i_ < 4; i_++) \
  _Pragma("unroll") for (int j_ = 0; j_ < 4; j_++) \
    acc[(IB) + i_][j_] = __builtin_amdgcn_mfma_f32_16x16x32_bf16(A4[i_], B4[j_], acc[(IB)+i_][j_], 0, 0, 0); \
} while (0)

// ---------------- kernel 0: W f32 -> bf16 hi/lo  w2 = [o][ wh(1024) | wl(1024) ] --
__global__ __launch_bounds__(256) void k_convW(const float* __restrict__ W,
                                               unsigned short* __restrict__ w2) {
    const int i8 = (blockIdx.x * 256 + threadIdx.x) * 8;
    const int o = i8 >> 10, h = i8 & 1023;
    float4 w0 = *(const float4*)(W + i8);
    float4 w1 = *(const float4*)(W + i8 + 4);
    float xs[8] = {w0.x, w0.y, w0.z, w0.w, w1.x, w1.y, w1.z, w1.w};
    us8 hv{}, lv{};
#pragma unroll
    for (int t = 0; t < 8; t++) {
        unsigned short xh = f2bf_rn(xs[t]);
        hv[t] = (unsigned short)xh;
        lv[t] = (unsigned short)f2bf_rn(xs[t] - bf2f(xh));
    }
    *(us8*)(w2 + (size_t)o * 2048 + h)        = hv;
    *(us8*)(w2 + (size_t)o * 2048 + 1024 + h) = lv;
}

// ------ kernel 1: fused (enc+hidden) @ W^T -> tanh -> dot(v) -> pscore16 ------
// LDS: A: slot(2) x [xh|xl] x [256][32] bf16 -> 64 KB   (slot*32768 + part*16384)
//      B: 65536 + slot(2) x [wh|wl] x [256][32] bf16 -> 64 KB
//      hidL: 131072 + 4 KB f32
__global__ __launch_bounds__(512, 2) void k_gemm_scores(
    const float* __restrict__ enc,
    const float* __restrict__ hidden,
    const unsigned short* __restrict__ w2,
    const float* __restrict__ b_attn,
    const float* __restrict__ v,
    float* __restrict__ pscore16)
{
    extern __shared__ char smem[];
    float* hidL = (float*)(smem + 131072);

    const int tid  = threadIdx.x;
    const int lane = tid & 63, wid = tid >> 6;
    const int wr = wid >> 2, wc = wid & 3;
    const int fr = lane & 15, g = lane >> 4;

    const int bid  = blockIdx.x;
    const int swz  = (bid & 7) * 128 + (bid >> 3);   // XCD-chunk swizzle (bijective, nwg=1024)
    const int mbase = (swz >> 2) * 256;
    const int nbase = (swz & 3) * 256;
    const int bidx  = mbase >> 11;                   // batch (BM=256 divides SEQ)

    // A conversion mapping: thread -> (row, 16-col half)
    const int arow = tid >> 1;
    const int acol = (tid & 1) * 16;
    const float* encP = enc + (size_t)(mbase + arow) * HID + acol;

    // B gload mapping
    const int brow  = wid * 16 + (lane >> 2);
    const int bcol8 = (lane & 3) * 8;

    // hidden row -> LDS (1024 f32)
    *(float2*)(hidL + tid * 2) = *(const float2*)(hidden + (size_t)bidx * HID + tid * 2);

    f32x4 acc[8][4];
#pragma unroll
    for (int i = 0; i < 8; i++)
#pragma unroll
        for (int j = 0; j < 4; j++) acc[i][j] = (f32x4)0.f;

    float4 er[4];

    auto loadEnc = [&](int Gn) {
        const float* ep = encP + Gn * 32;
#pragma unroll
        for (int q = 0; q < 4; q++) er[q] = *(const float4*)(ep + q * 4);
    };
    auto convA = [&](int Gn) {
        char* ap = smem + (Gn & 1) * 32768 + arow * 64 + acol * 2;
        const float* hp = hidL + Gn * 32 + acol;
        us8 hv0{}, hv1{}, lv0{}, lv1{};
#pragma unroll
        for (int q = 0; q < 4; q++) {
            float4 e = er[q];
            float4 h = *(const float4*)(hp + q * 4);
            float xs[4] = {e.x + h.x, e.y + h.y, e.z + h.z, e.w + h.w};
#pragma unroll
            for (int t = 0; t < 4; t++) {
                unsigned short xh = f2bf_rn(xs[t]);
                unsigned short xl = f2bf_rn(xs[t] - bf2f(xh));
                const int p = q * 4 + t;
                if (p < 8) { hv0[p] = xh; lv0[p] = xl; }
                else       { hv1[p - 8] = xh; lv1[p - 8] = xl; }
            }
        }
        *(us8*)ap                 = hv0;
        *(us8*)(ap + 16)          = hv1;
        *(us8*)(ap + 16384)       = lv0;
        *(us8*)(ap + 16384 + 16)  = lv1;
    };
    auto stageB = [&](int G2, int part) {   // part: 0=wh, 1=wl ; 2 gloads
        const unsigned short* s0 = w2 + (size_t)(nbase + brow) * 2048 + part * 1024 + G2 * 32 + bcol8;
        char* d0 = smem + 65536 + (G2 & 1) * 32768 + part * 16384 + wid * 1024;
        gload16(s0, d0);
        gload16(s0 + (size_t)128 * 2048, d0 + 8192);
    };
    auto rdA = [&](int slot, int part, int i) -> bf16x8 {
        return *(const bf16x8*)(smem + slot * 32768 + part * 16384 +
                                (wr * 128 + i * 16 + fr) * 64 + g * 16);
    };
    auto rdB = [&](int slot, int part, int j) -> bf16x8 {
        return *(const bf16x8*)(smem + 65536 + slot * 32768 + part * 16384 +
                                (wc * 64 + j * 16 + fr) * 64 + g * 16);
    };

    // ---- prologue: enc(0) regs; B(0),B(1) gloads; A(0) -> LDS ----
    loadEnc(0);
    stageB(0, 0); stageB(0, 1);
    stageB(1, 0); stageB(1, 1);
    asm volatile("s_waitcnt lgkmcnt(0)" ::: "memory");   // hidL ready
    __builtin_amdgcn_s_barrier(); FENCE();
    convA(0);                                            // compiler drains enc(0) here

    bf16x8 aa[4], bh[4], bl[4];

    for (int G = 0; G < NG; ++G) {
        const int slot = G & 1;
        // ---------- ph1: read xh(i0-3) + wh + wl; issue enc(G+1); MFMA xh*wh lo ----------
        BAR_VM4();                                       // B(G) guaranteed complete
#pragma unroll
        for (int i = 0; i < 4; i++) aa[i] = rdA(slot, 0, i);
#pragma unroll
        for (int j = 0; j < 4; j++) bh[j] = rdB(slot, 0, j);
#pragma unroll
        for (int j = 0; j < 4; j++) bl[j] = rdB(slot, 1, j);
        if (G + 1 < NG) loadEnc(G + 1);
        __builtin_amdgcn_s_setprio(1);
        MFMA_BLK(aa, bh, 0);
        __builtin_amdgcn_s_setprio(0);
        // ---------- ph2: issue B wh(G+2); MFMA xh*wl lo ----------
        BAR_LG();
        if (G + 2 < NG) stageB(G + 2, 0);
        __builtin_amdgcn_s_setprio(1);
        MFMA_BLK(aa, bl, 0);
        __builtin_amdgcn_s_setprio(0);
        // ---------- ph3: read xh(i4-7); issue B wl(G+2); MFMA xh*wh hi ----------
        BAR_LG();
#pragma unroll
        for (int i = 0; i < 4; i++) aa[i] = rdA(slot, 0, 4 + i);
        if (G + 2 < NG) stageB(G + 2, 1);
        __builtin_amdgcn_s_setprio(1);
        MFMA_BLK(aa, bh, 4);
        __builtin_amdgcn_s_setprio(0);
        // ---------- ph4: convert+write A(G+1); MFMA xh*wl hi ----------
        BAR_LG();
        if (G + 1 < NG) convA(G + 1);
        __builtin_amdgcn_s_setprio(1);
        MFMA_BLK(aa, bl, 4);
        __builtin_amdgcn_s_setprio(0);
        // ---------- ph5: read xl(i0-3); MFMA xl*wh lo ----------
        BAR_LG();
#pragma unroll
        for (int i = 0; i < 4; i++) aa[i] = rdA(slot, 1, i);
        __builtin_amdgcn_s_setprio(1);
        MFMA_BLK(aa, bh, 0);
        __builtin_amdgcn_s_setprio(0);
        // ---------- ph6: read xl(i4-7); MFMA xl*wh hi ----------
        BAR_LG();
#pragma unroll
        for (int i = 0; i < 4; i++) aa[i] = rdA(slot, 1, 4 + i);
        __builtin_amdgcn_s_setprio(1);
        MFMA_BLK(aa, bh, 4);
        __builtin_amdgcn_s_setprio(0);
    }

    // ---- epilogue: tanh(e+b)*v, reduce over cols, write 1 plane per (nblk,wc) ----
    float rs[8][4];
#pragma unroll
    for (int i = 0; i < 8; i++)
#pragma unroll
        for (int r = 0; r < 4; r++) rs[i][r] = 0.f;

#pragma unroll
    for (int j = 0; j < 4; j++) {
        const int n = nbase + wc * 64 + j * 16 + fr;
        const float ba = b_attn[n];
        const float vv = v[n];
#pragma unroll
        for (int i = 0; i < 8; i++)
#pragma unroll
            for (int r = 0; r < 4; r++) {
                float e  = acc[i][j][r] + ba;
                float ex = __expf(2.f * e);
                rs[i][r] += (1.f - 2.f / (ex + 1.f)) * vv;
            }
    }
#pragma unroll
    for (int off = 1; off < 16; off <<= 1)
#pragma unroll
        for (int i = 0; i < 8; i++)
#pragma unroll
            for (int r = 0; r < 4; r++) rs[i][r] += __shfl_xor(rs[i][r], off, 64);

    float v0 = 0.f, v1 = 0.f;
#pragma unroll
    for (int i = 0; i < 4; i++)
#pragma unroll
        for (int r = 0; r < 4; r++)
            if (fr == i * 4 + r) { v0 = rs[i][r]; v1 = rs[i + 4][r]; }

    const int plane = (swz & 3) * 4 + wc;
    const size_t pb = (size_t)plane * M_TOT + mbase + wr * 128 + g * 4 + (fr & 3);
    pscore16[pb + (fr >> 2) * 16]      = v0;
    pscore16[pb + (fr >> 2) * 16 + 64] = v1;
}

// ---------------- kernel 2: sum 16 partial planes + softmax over S ----------
__global__ __launch_bounds__(256) void k_softmax(const float* __restrict__ ps,
                                                 float* __restrict__ out) {
    const int b = blockIdx.x, t = threadIdx.x;
    __shared__ float red[8];
    float loc[8];
    float lmax = -1e30f;
#pragma unroll
    for (int i = 0; i < 8; i++) {
        const int s = t + i * 256;
        float sc = 0.f;
#pragma unroll
        for (int p = 0; p < 16; p++) sc += ps[(size_t)p * M_TOT + (size_t)b * SEQ + s];
        loc[i] = sc;
        lmax = fmaxf(lmax, sc);
    }
    for (int o = 32; o; o >>= 1) lmax = fmaxf(lmax, __shfl_xor(lmax, o, 64));
    if ((t & 63) == 0) red[t >> 6] = lmax;
    __syncthreads();
    const float bmax = fmaxf(fmaxf(red[0], red[1]), fmaxf(red[2], red[3]));
    float ev[8], lsum = 0.f;
#pragma unroll
    for (int i = 0; i < 8; i++) { ev[i] = expf(loc[i] - bmax); lsum += ev[i]; }
    for (int o = 32; o; o >>= 1) lsum += __shfl_xor(lsum, o, 64);
    __syncthreads();
    if ((t & 63) == 0) red[4 + (t >> 6)] = lsum;
    __syncthreads();
    const float inv = 1.f / (red[4] + red[5] + red[6] + red[7]);
#pragma unroll
    for (int i = 0; i < 8; i++)
        out[(size_t)BATCH * HID + (size_t)b * SEQ + t + i * 256] = ev[i] * inv;
}

// ---------------- kernel 3: partial context over S-chunks -------------------
__global__ __launch_bounds__(256) void k_pctx(const float* __restrict__ enc,
                                              const float* __restrict__ attn,
                                              float* __restrict__ pctx) {
    const int hc = blockIdx.x, scb = blockIdx.y, b = blockIdx.z;
    const int h = hc * 256 + threadIdx.x;
    const float* ap = attn + (size_t)b * SEQ + scb * 256;
    const float* ep = enc + ((size_t)b * SEQ + scb * 256) * HID + h;
    float a = 0.f;
#pragma unroll 4
    for (int s = 0; s < 256; s++) a += ap[s] * ep[(size_t)s * HID];
    pctx[((size_t)scb * BATCH + b) * HID + h] = a;
}

// ---------------- kernel 4: reduce partial contexts -------------------------
__global__ __launch_bounds__(256) void k_ctx(const float* __restrict__ pctx,
                                             float* __restrict__ out) {
    const int i = blockIdx.x * 256 + threadIdx.x;
    float a = 0.f;
#pragma unroll
    for (int p = 0; p < 8; p++) a += pctx[(size_t)p * BATCH * HID + i];
    out[i] = a;
}

extern "C" void kernel_launch(void* const* d_in, const int* in_sizes, int n_in,
                              void* d_out, int out_size, void* d_ws, size_t ws_size,
                              hipStream_t stream) {
    const float* hidden = (const float*)d_in[0];
    const float* enc    = (const float*)d_in[1];
    const float* W      = (const float*)d_in[2];
    const float* b_attn = (const float*)d_in[3];
    const float* v      = (const float*)d_in[4];
    float* out = (float*)d_out;

    char* ws = (char*)d_ws;
    unsigned short* w2 = (unsigned short*)ws;                 // 4 MB (dead after gemm)
    float* pscore16    = (float*)(ws + ((size_t)4 << 20));    // 4 MB
    float* pctx        = (float*)ws;                          // reuses w2 region post-gemm

    const int smemBytes = 131072 + 4096;
    hipFuncSetAttribute((const void*)k_gemm_scores,
                        hipFuncAttributeMaxDynamicSharedMemorySize, smemBytes);

    k_convW<<<dim3(512), dim3(256), 0, stream>>>(W, w2);
    k_gemm_scores<<<dim3(1024), dim3(512), smemBytes, stream>>>(
        enc, hidden, w2, b_attn, v, pscore16);
    k_softmax<<<dim3(BATCH), dim3(256), 0, stream>>>(pscore16, out);
    k_pctx<<<dim3(4, 8, BATCH), dim3(256), 0, stream>>>(enc, out + BATCH * HID, pctx);
    k_ctx<<<dim3(128), dim3(256), 0, stream>>>(pctx, out);
}